// Round 5
// baseline (308.392 us; speedup 1.0000x reference)
//
#include <hip/hip_runtime.h>
#include <hip/hip_bf16.h>

// Problem constants (from reference)
#define E_EDGES 262144
#define B_SAMP  1024
#define L_SEQ   10
#define T_SEG   (B_SAMP * L_SEQ)   // 10240 segments
#define H_DIM   128
#define N_ENT_C 40000
#define N_REL_C 256

__device__ __forceinline__ float b2f(__hip_bfloat16 x) { return __bfloat162float(x); }
__device__ __forceinline__ __hip_bfloat16 f2b(float x) { return __float2bfloat16(x); }

// Float load with runtime-detected storage (bf16 vs float32).
__device__ __forceinline__ float loadF(const void* base, int idx, int isB16) {
    if (isB16) return b2f(((const __hip_bfloat16*)base)[idx]);
    return ((const float*)base)[idx];
}
// Integer load with runtime-detected width (int64 vs int32).
__device__ __forceinline__ int loadI(const void* base, int idx, int is64) {
    if (is64) return (int)(((const long long*)base)[idx]);
    return ((const int*)base)[idx];
}
// Projection-table element access (float or bf16 storage).
__device__ __forceinline__ float toF(float x) { return x; }
__device__ __forceinline__ float toF(__hip_bfloat16 x) { return b2f(x); }
__device__ __forceinline__ void stP(float& d, float v) { d = v; }
__device__ __forceinline__ void stP(__hip_bfloat16& d, float v) { d = f2b(v); }

// ---------------------------------------------------------------------------
// D0: float-storage detection on nbr_att (uniform[0,1)).
// bf16 buffer: ~100% of first 2048 uint16 words <= 0x3F80. f32 buffer: odd
// words in range, even words random mantissa (~25%) -> ~62%. Threshold 1900.
// ---------------------------------------------------------------------------
__global__ void detect_float_kernel(const void* __restrict__ att_raw,
                                    int* __restrict__ flag)
{
    __shared__ int cnt;
    if (threadIdx.x == 0) cnt = 0;
    __syncthreads();
    const unsigned short* p = (const unsigned short*)att_raw;
    int c = 0;
    for (int i = threadIdx.x; i < 2048; i += 256) {
        if (p[i] <= 0x3F80u) c++;
    }
    atomicAdd(&cnt, c);
    __syncthreads();
    if (threadIdx.x == 0) *flag = (cnt >= 1900) ? 1 : 0;
}

// ---------------------------------------------------------------------------
// D1: int-width detection on s_ids. int64 storage: odd int32 words are zero
// high words (~512 of 512). int32: odd words are real ids (~0 zeros).
// ---------------------------------------------------------------------------
__global__ void detect_int_kernel(const void* __restrict__ sid_raw,
                                  int* __restrict__ iflag)
{
    __shared__ int cnt;
    if (threadIdx.x == 0) cnt = 0;
    __syncthreads();
    const int* p = (const int*)sid_raw;
    int c = 0;
    for (int i = threadIdx.x; i < 512; i += 256) {
        if (p[2 * i + 1] == 0) c++;
    }
    atomicAdd(&cnt, c);
    __syncthreads();
    if (threadIdx.x == 0) *iflag = (cnt >= 256) ? 1 : 0;
}

// ---------------------------------------------------------------------------
// P0: weight tables, k-major.
//  wctE[k][n] (n<128 -> W3[n][128+k], else W4[n-128][k])        [128][256] f32
//  wctR[k][n] (n<128 -> W3[n][256+k], else W4[n-128][128+k])    [128][256] f32
//  W3att[h][k] = W3[h][k]  (att block)                          [128][128] f32
// ---------------------------------------------------------------------------
__global__ void prep_tables(const void* __restrict__ W3w,
                            const void* __restrict__ W4w,
                            const int* __restrict__ flag,
                            float* __restrict__ wctE,
                            float* __restrict__ wctR,
                            float* __restrict__ W3att)
{
    const int isB = *flag;
    int i = blockIdx.x * 256 + threadIdx.x;
    if (i < 32768) {
        int k = i >> 8, n = i & 255;
        wctE[i] = (n < 128) ? loadF(W3w, n * 384 + 128 + k, isB)
                            : loadF(W4w, (n - 128) * 256 + k, isB);
    } else if (i < 65536) {
        int j = i - 32768;
        int k = j >> 8, n = j & 255;
        wctR[j] = (n < 128) ? loadF(W3w, n * 384 + 256 + k, isB)
                            : loadF(W4w, (n - 128) * 256 + 128 + k, isB);
    } else if (i < 81920) {
        int j = i - 65536;   // h*128 + k
        W3att[j] = loadF(W3w, (j >> 7) * 384 + (j & 127), isB);
    }
}

// ---------------------------------------------------------------------------
// P1: fp32 scalar vectors + sorted relu-kink breakpoints of the att proj.
// ---------------------------------------------------------------------------
__global__ void prep_scalars(const void* __restrict__ W1w,
                             const void* __restrict__ W1b,
                             const void* __restrict__ W3b,
                             const void* __restrict__ W4b,
                             const int* __restrict__ flag,
                             float* __restrict__ W1w_f,
                             float* __restrict__ W1b_f,
                             float* __restrict__ W3b_f,
                             float* __restrict__ W4b_f,
                             float* __restrict__ bpts,
                             int* __restrict__ pnIn)
{
    const int isB = *flag;
    const int tid = threadIdx.x;  // 128
    float w = loadF(W1w, tid, isB);
    float b = loadF(W1b, tid, isB);
    W1w_f[tid] = w;
    W1b_f[tid] = b;
    W3b_f[tid] = loadF(W3b, tid, isB);
    W4b_f[tid] = loadF(W4b, tid, isB);

    __shared__ float thr[128];
    float t = 2.0f;  // sentinel: no kink inside (0,1)
    if (w != 0.0f) {
        float tt = -b / w;
        if (tt > 0.0f && tt < 1.0f) t = tt;
    }
    thr[tid] = t;
    __syncthreads();

    for (int ph = 0; ph < 128; ++ph) {   // odd-even transposition sort
        int i = 2 * tid + (ph & 1);
        if (tid < 64 && i + 1 < 128) {
            float a0 = thr[i], a1 = thr[i + 1];
            if (a0 > a1) { thr[i] = a1; thr[i + 1] = a0; }
        }
        __syncthreads();
    }

    int nIn = 0;
    for (int i = 0; i < 128; ++i)
        if (thr[i] < 1.5f) nIn++;
    bpts[tid] = thr[tid];
    if (tid == 0) *pnIn = nIn;
}

// ---------------------------------------------------------------------------
// P2: per-interval att-projection tables (exact piecewise-linear reassoc).
//   A3[j][h] = sum_{k active in interval j} w1[k] * W3att[h][k]
//   B3[j][h] = sum_{k active}               b1[k] * W3att[h][k]
// per edge: att-block contribution = att * A3[j] + B3[j]
// ---------------------------------------------------------------------------
__global__ void att_table_kernel(const float* __restrict__ W1w_f,
                                 const float* __restrict__ W1b_f,
                                 const float* __restrict__ W3att,
                                 const float* __restrict__ bpts,
                                 const int* __restrict__ pnIn,
                                 float* __restrict__ A3,
                                 float* __restrict__ B3)
{
    const int j = blockIdx.x;
    const int nIn = *pnIn;
    if (j > nIn) return;
    const int h = threadIdx.x;

    __shared__ float w1s[128], b1s[128];
    w1s[h] = W1w_f[h];
    b1s[h] = W1b_f[h];
    __syncthreads();

    float left  = (j == 0)   ? 0.0f : bpts[j - 1];
    float right = (j == nIn) ? 1.0f : bpts[j];
    float mid = 0.5f * (left + right);

    float a = 0.0f, b = 0.0f;
    const float* wrow = W3att + h * 128;
    #pragma unroll 4
    for (int k = 0; k < 128; ++k) {
        if (mid * w1s[k] + b1s[k] > 0.0f) {
            float w3 = wrow[k];
            a += w1s[k] * w3;
            b += b1s[k] * w3;
        }
    }
    A3[j * 128 + h] = a;
    B3[j * 128 + h] = b;
}

// ---------------------------------------------------------------------------
// G: VALU GEMM  out[M][256] = A[M][128] @ WT  (WT is [128][256] k-major).
// Block: 16 rows, 256 threads (one output column each), f32 accumulate.
// PT = float or __hip_bfloat16 storage for the projection table.
// ---------------------------------------------------------------------------
template <typename PT>
__global__ void __launch_bounds__(256)
gemm_valu(const void* __restrict__ A_raw, const int* __restrict__ flag,
          const float* __restrict__ WT,
          PT* __restrict__ out, int M)
{
    const int isB = *flag;
    const int m0 = blockIdx.x * 16;
    const int c  = threadIdx.x;

    __shared__ float As[16][128];
    for (int i = threadIdx.x; i < 16 * 128; i += 256) {
        int r = i >> 7, k = i & 127;
        As[r][k] = loadF(A_raw, (m0 + r) * 128 + k, isB);
    }
    __syncthreads();

    float acc[16];
    #pragma unroll
    for (int r = 0; r < 16; ++r) acc[r] = 0.0f;

    for (int kk = 0; kk < 32; ++kk) {
        float w0 = WT[(kk * 4 + 0) * 256 + c];
        float w1 = WT[(kk * 4 + 1) * 256 + c];
        float w2 = WT[(kk * 4 + 2) * 256 + c];
        float w3 = WT[(kk * 4 + 3) * 256 + c];
        #pragma unroll
        for (int r = 0; r < 16; ++r) {
            const float4 a = *reinterpret_cast<const float4*>(&As[r][kk * 4]);
            acc[r] = fmaf(a.x, w0, fmaf(a.y, w1, fmaf(a.z, w2, fmaf(a.w, w3, acc[r]))));
        }
    }

    for (int r = 0; r < 16; ++r)
        stP(out[(size_t)(m0 + r) * 256 + c], acc[r]);
}

// ---------------------------------------------------------------------------
// S0: segment start offsets via lower_bound on sorted seg_ids.
// ---------------------------------------------------------------------------
__global__ void seg_start_kernel(const void* __restrict__ seg_ids,
                                 const int* __restrict__ iflag,
                                 int* __restrict__ starts)
{
    int t = blockIdx.x * blockDim.x + threadIdx.x;
    if (t > T_SEG) return;
    const int i64 = *iflag;
    int lo = 0, hi = E_EDGES;
    while (lo < hi) {
        int m = (lo + hi) >> 1;
        if (loadI(seg_ids, m, i64) < t) lo = m + 1; else hi = m;
    }
    starts[t] = lo;
}

// ---------------------------------------------------------------------------
// S1: per-edge att interval index (count of breakpoints <= att).
// ---------------------------------------------------------------------------
__global__ void edge_bucket_kernel(const void* __restrict__ att_raw,
                                   const int* __restrict__ flag,
                                   const float* __restrict__ bpts,
                                   const int* __restrict__ pnIn,
                                   unsigned char* __restrict__ j_edge)
{
    int i = blockIdx.x * blockDim.x + threadIdx.x;
    if (i >= E_EDGES) return;
    float att = loadF(att_raw, i, *flag);
    int nIn = *pnIn;
    int lo = 0, hi = nIn;
    while (lo < hi) {
        int m = (lo + hi) >> 1;
        if (bpts[m] <= att) lo = m + 1; else hi = m;
    }
    j_edge[i] = (unsigned char)lo;
}

// ---------------------------------------------------------------------------
// Shared epilogue: self parts + direct writes into concatenated FP32 output.
//   outS[t] = [ ent[s_ids[b]], rel[r_ids[b]], mean_static ]
//   outA[t] = [ relu(self_att*w1+b1), ent[s_ids[b]], mean ]
// ---------------------------------------------------------------------------
__device__ __forceinline__ void write_outputs(
    int t, int h, float acc3, float acc4, int cnt,
    const void* ent_raw, const void* rel_raw, const void* sat_raw,
    int isB, int i64,
    const void* s_ids, const void* r_ids,
    const float* W1w_f, const float* W1b_f,
    float* outS, float* outA)
{
    float inv = (cnt > 0) ? (1.0f / (float)cnt) : 1.0f;
    const int b = t / L_SEQ;
    int sid = loadI(s_ids, b, i64);
    int rid = loadI(r_ids, b, i64);
    float se = loadF(ent_raw, sid * 128 + h, isB);
    float sr = loadF(rel_raw, rid * 128 + h, isB);
    float sa  = loadF(sat_raw, t, isB);
    float sae = fmaxf(fmaf(sa, W1w_f[h], W1b_f[h]), 0.0f);

    const size_t base = (size_t)t * 384;
    outS[base + h]       = se;
    outS[base + 128 + h] = sr;
    outS[base + 256 + h] = acc4 * inv;
    outA[base + h]       = sae;
    outA[base + 128 + h] = se;
    outA[base + 256 + h] = acc3 * inv;
}

// ---------------------------------------------------------------------------
// S2 (fast): per-segment aggregation using precomputed entp/relp tables.
//   entp[m][n]: n<128 -> P3s[m][n], n>=128 -> P4s[m][n-128]. relp likewise.
// ---------------------------------------------------------------------------
template <typename PT>
__global__ void __launch_bounds__(128)
segment_fast(const void* __restrict__ nbr_ent,
             const void* __restrict__ nbr_rel,
             const void* __restrict__ att_raw,
             const unsigned char* __restrict__ j_edge,
             const int* __restrict__ starts,
             const PT* __restrict__ entp,
             const PT* __restrict__ relp,
             const float* __restrict__ A3,
             const float* __restrict__ B3,
             const float* __restrict__ W3b_f,
             const float* __restrict__ W4b_f,
             const void* __restrict__ sat_raw,
             const void* __restrict__ s_ids,
             const void* __restrict__ r_ids,
             const void* __restrict__ ent_raw,
             const void* __restrict__ rel_raw,
             const float* __restrict__ W1w_f,
             const float* __restrict__ W1b_f,
             const int* __restrict__ flag,
             const int* __restrict__ iflag,
             float* __restrict__ outS,
             float* __restrict__ outA)
{
    const int t = blockIdx.x;
    const int h = threadIdx.x;
    const int isB = *flag;
    const int i64 = *iflag;
    const int s = starts[t];
    const int e = starts[t + 1];

    const float b3h = W3b_f[h];
    const float b4h = W4b_f[h];

    float acc3 = 0.0f, acc4 = 0.0f;
    for (int i = s; i < e; ++i) {
        int ent = loadI(nbr_ent, i, i64);
        int rel = loadI(nbr_rel, i, i64);
        float att = loadF(att_raw, i, isB);
        int j = j_edge[i];
        float a3  = A3[j * 128 + h];
        float bb3 = B3[j * 128 + h];
        float p3s = toF(entp[ent * 256 + h]);
        float p4s = toF(entp[ent * 256 + 128 + h]);
        float p3r = toF(relp[rel * 256 + h]);
        float p4r = toF(relp[rel * 256 + 128 + h]);
        float z3 = fmaf(att, a3, bb3) + p3s + p3r + b3h;
        float z4 = p4s + p4r + b4h;
        acc3 += fmaxf(z3, 0.0f);
        acc4 += fmaxf(z4, 0.0f);
    }
    write_outputs(t, h, acc3, acc4, e - s, ent_raw, rel_raw, sat_raw, isB, i64,
                  s_ids, r_ids, W1w_f, W1b_f, outS, outA);
}

// ---------------------------------------------------------------------------
// S2 (slow fallback, no big scratch): projections computed inline per edge.
// ---------------------------------------------------------------------------
__global__ void __launch_bounds__(128)
segment_slow(const void* __restrict__ nbr_ent,
             const void* __restrict__ nbr_rel,
             const void* __restrict__ att_raw,
             const unsigned char* __restrict__ j_edge,
             const int* __restrict__ starts,
             const float* __restrict__ wctE,   // [128][256] k-major
             const float* __restrict__ wctR,
             const float* __restrict__ A3,
             const float* __restrict__ B3,
             const float* __restrict__ W3b_f,
             const float* __restrict__ W4b_f,
             const void* __restrict__ sat_raw,
             const void* __restrict__ s_ids,
             const void* __restrict__ r_ids,
             const void* __restrict__ ent_raw,
             const void* __restrict__ rel_raw,
             const float* __restrict__ W1w_f,
             const float* __restrict__ W1b_f,
             const int* __restrict__ flag,
             const int* __restrict__ iflag,
             float* __restrict__ outS,
             float* __restrict__ outA)
{
    const int t = blockIdx.x;
    const int h = threadIdx.x;
    const int isB = *flag;
    const int i64 = *iflag;
    const int s = starts[t];
    const int e = starts[t + 1];

    const float b3h = W3b_f[h];
    const float b4h = W4b_f[h];

    __shared__ float es[128], er[128];

    float acc3 = 0.0f, acc4 = 0.0f;
    for (int i = s; i < e; ++i) {
        int ent = loadI(nbr_ent, i, i64);
        int rel = loadI(nbr_rel, i, i64);
        __syncthreads();
        es[h] = loadF(ent_raw, ent * 128 + h, isB);
        er[h] = loadF(rel_raw, rel * 128 + h, isB);
        __syncthreads();
        float p3 = 0.0f, p4 = 0.0f;
        for (int k = 0; k < 128; ++k) {
            float a = es[k], r = er[k];
            p3 = fmaf(a, wctE[k * 256 + h],       fmaf(r, wctR[k * 256 + h],       p3));
            p4 = fmaf(a, wctE[k * 256 + 128 + h], fmaf(r, wctR[k * 256 + 128 + h], p4));
        }
        float att = loadF(att_raw, i, isB);
        int j = j_edge[i];
        float z3 = fmaf(att, A3[j * 128 + h], B3[j * 128 + h]) + p3 + b3h;
        float z4 = p4 + b4h;
        acc3 += fmaxf(z3, 0.0f);
        acc4 += fmaxf(z4, 0.0f);
    }
    write_outputs(t, h, acc3, acc4, e - s, ent_raw, rel_raw, sat_raw, isB, i64,
                  s_ids, r_ids, W1w_f, W1b_f, outS, outA);
}

// ---------------------------------------------------------------------------
extern "C" void kernel_launch(void* const* d_in, const int* in_sizes, int n_in,
                              void* d_out, int out_size, void* d_ws, size_t ws_size,
                              hipStream_t stream)
{
    const void* nbr_ent = d_in[0];
    const void* nbr_rel = d_in[1];
    const void* nbr_att = d_in[2];
    const void* seg_ids = d_in[3];
    const void* self_att = d_in[4];
    const void* s_ids = d_in[5];
    const void* r_ids = d_in[6];
    const void* ent_embeds = d_in[7];
    const void* rel_embeds = d_in[8];
    const void* W1w = d_in[9];
    const void* W1b = d_in[10];
    const void* W3w = d_in[11];
    const void* W3b = d_in[12];
    const void* W4w = d_in[13];
    const void* W4b = d_in[14];

    // workspace carve-up: small buffers FIRST, big projection tables LAST.
    char* ws = (char*)d_ws;
    size_t off = 0;
    auto alloc = [&](size_t bytes) -> void* {
        void* p = ws + off;
        off = (off + bytes + 255) & ~(size_t)255;
        return p;
    };
    int*   flag   = (int*)alloc(4);
    int*   iflag  = (int*)alloc(4);
    int*   pnIn   = (int*)alloc(4);
    float* W1w_f  = (float*)alloc(128 * 4);
    float* W1b_f  = (float*)alloc(128 * 4);
    float* W3b_f  = (float*)alloc(128 * 4);
    float* W4b_f  = (float*)alloc(128 * 4);
    float* bpts   = (float*)alloc(128 * 4);
    int*   starts = (int*)alloc((T_SEG + 1) * 4);
    unsigned char* j_edge = (unsigned char*)alloc(E_EDGES);
    float* wctE   = (float*)alloc(128 * 256 * 4);
    float* wctR   = (float*)alloc(128 * 256 * 4);
    float* W3att  = (float*)alloc(128 * 128 * 4);
    float* A3     = (float*)alloc(129 * 128 * 4);
    float* B3     = (float*)alloc(129 * 128 * 4);
    size_t off_small = off;

    // Tier A: f32 projection tables (~42 MB total)
    float* entp_f = (float*)alloc((size_t)N_ENT_C * 256 * 4);
    float* relp_f = (float*)alloc((size_t)N_REL_C * 256 * 4);
    size_t need_f32 = off;
    // Tier B: bf16 projection tables (~21.4 MB total) — aliases Tier A space
    off = off_small;
    __hip_bfloat16* entp_b = (__hip_bfloat16*)alloc((size_t)N_ENT_C * 256 * 2);
    __hip_bfloat16* relp_b = (__hip_bfloat16*)alloc((size_t)N_REL_C * 256 * 2);
    size_t need_b16 = off;

    const int tier = (ws_size >= need_f32) ? 0 : (ws_size >= need_b16 ? 1 : 2);

    float* outS = (float*)d_out;
    float* outA = outS + (size_t)T_SEG * 384;

    // D0/D1: runtime dtype detection (float storage + int width)
    detect_float_kernel<<<1, 256, 0, stream>>>(nbr_att, flag);
    detect_int_kernel<<<1, 256, 0, stream>>>(s_ids, iflag);

    // P0/P1: weight tables + scalar vectors + breakpoints
    prep_tables<<<320, 256, 0, stream>>>(W3w, W4w, flag, wctE, wctR, W3att);
    prep_scalars<<<1, 128, 0, stream>>>(W1w, W1b, W3b, W4b, flag,
                                        W1w_f, W1b_f, W3b_f, W4b_f, bpts, pnIn);

    // P2: att piecewise tables
    att_table_kernel<<<129, 128, 0, stream>>>(W1w_f, W1b_f, W3att, bpts, pnIn, A3, B3);

    // S0/S1: segment starts + per-edge att bucket
    seg_start_kernel<<<(T_SEG + 1 + 255) / 256, 256, 0, stream>>>(seg_ids, iflag, starts);
    edge_bucket_kernel<<<E_EDGES / 256, 256, 0, stream>>>(nbr_att, flag, bpts, pnIn, j_edge);

    if (tier == 0) {
        gemm_valu<float><<<N_ENT_C / 16, 256, 0, stream>>>(ent_embeds, flag, wctE, entp_f, N_ENT_C);
        gemm_valu<float><<<N_REL_C / 16, 256, 0, stream>>>(rel_embeds, flag, wctR, relp_f, N_REL_C);
        segment_fast<float><<<T_SEG, 128, 0, stream>>>(
            nbr_ent, nbr_rel, nbr_att, j_edge, starts, entp_f, relp_f, A3, B3,
            W3b_f, W4b_f, self_att, s_ids, r_ids, ent_embeds, rel_embeds,
            W1w_f, W1b_f, flag, iflag, outS, outA);
    } else if (tier == 1) {
        gemm_valu<__hip_bfloat16><<<N_ENT_C / 16, 256, 0, stream>>>(ent_embeds, flag, wctE, entp_b, N_ENT_C);
        gemm_valu<__hip_bfloat16><<<N_REL_C / 16, 256, 0, stream>>>(rel_embeds, flag, wctR, relp_b, N_REL_C);
        segment_fast<__hip_bfloat16><<<T_SEG, 128, 0, stream>>>(
            nbr_ent, nbr_rel, nbr_att, j_edge, starts, entp_b, relp_b, A3, B3,
            W3b_f, W4b_f, self_att, s_ids, r_ids, ent_embeds, rel_embeds,
            W1w_f, W1b_f, flag, iflag, outS, outA);
    } else {
        segment_slow<<<T_SEG, 128, 0, stream>>>(
            nbr_ent, nbr_rel, nbr_att, j_edge, starts, wctE, wctR, A3, B3,
            W3b_f, W4b_f, self_att, s_ids, r_ids, ent_embeds, rel_embeds,
            W1w_f, W1b_f, flag, iflag, outS, outA);
    }
}

// Round 6
// 215.981 us; speedup vs baseline: 1.4279x; 1.4279x over previous
//
#include <hip/hip_runtime.h>
#include <hip/hip_bf16.h>

// Problem constants (from reference)
#define E_EDGES 262144
#define B_SAMP  1024
#define L_SEQ   10
#define T_SEG   (B_SAMP * L_SEQ)   // 10240 segments
#define H_DIM   128
#define N_ENT_C 40000
#define N_REL_C 256

typedef __attribute__((ext_vector_type(8))) short short8;   // 8 bf16 (4 VGPRs)
typedef __attribute__((ext_vector_type(4))) float f32x4;

__device__ __forceinline__ float b2f(__hip_bfloat16 x) { return __bfloat162float(x); }
__device__ __forceinline__ unsigned short f2bu(float x) {
    return __bfloat16_as_ushort(__float2bfloat16(x));
}
__device__ __forceinline__ float bu2f(unsigned short u) {
    return b2f(__ushort_as_bfloat16(u));
}

// Float load with runtime-detected storage (bf16 vs float32).
__device__ __forceinline__ float loadF(const void* base, int idx, int isB16) {
    if (isB16) return b2f(((const __hip_bfloat16*)base)[idx]);
    return ((const float*)base)[idx];
}
// Integer load with runtime-detected width (int64 vs int32).
__device__ __forceinline__ int loadI(const void* base, int idx, int is64) {
    if (is64) return (int)(((const long long*)base)[idx]);
    return ((const int*)base)[idx];
}

// ---------------------------------------------------------------------------
// K1 (1 block, 256 thr): dtype detection + fp32 scalar vectors + sorted
// relu-kink breakpoints of the att projection (t_k = -b1k/w1k in (0,1)).
// ---------------------------------------------------------------------------
__global__ void k1_prep(const void* __restrict__ att_raw,
                        const void* __restrict__ sid_raw,
                        const void* __restrict__ W1w, const void* __restrict__ W1b,
                        const void* __restrict__ W3b, const void* __restrict__ W4b,
                        int* __restrict__ flag, int* __restrict__ iflag,
                        float* __restrict__ W1w_f, float* __restrict__ W1b_f,
                        float* __restrict__ W3b_f, float* __restrict__ W4b_f,
                        float* __restrict__ bpts, int* __restrict__ pnIn)
{
    __shared__ int cF, cI, sF;
    __shared__ float thr[128];
    const int tid = threadIdx.x;  // 256
    if (tid == 0) { cF = 0; cI = 0; }
    __syncthreads();

    // float storage detect: bf16 uniform[0,1) -> ~100% words <= 0x3F80;
    // f32 -> ~62%. Threshold 1900/2048.
    const unsigned short* pa = (const unsigned short*)att_raw;
    int c = 0;
    for (int i = tid; i < 2048; i += 256) if (pa[i] <= 0x3F80u) c++;
    atomicAdd(&cF, c);
    // int width detect: int64 -> odd int32 words are zero high-words.
    const int* ps = (const int*)sid_raw;
    c = 0;
    for (int i = tid; i < 512; i += 256) if (ps[2 * i + 1] == 0) c++;
    atomicAdd(&cI, c);
    __syncthreads();
    if (tid == 0) {
        sF = (cF >= 1900) ? 1 : 0;
        *flag = sF;
        *iflag = (cI >= 256) ? 1 : 0;
    }
    __syncthreads();
    const int isB = sF;

    if (tid < 128) {
        float w = loadF(W1w, tid, isB);
        float b = loadF(W1b, tid, isB);
        W1w_f[tid] = w; W1b_f[tid] = b;
        W3b_f[tid] = loadF(W3b, tid, isB);
        W4b_f[tid] = loadF(W4b, tid, isB);
        float t = 2.0f;  // sentinel: no kink inside (0,1)
        if (w != 0.0f) {
            float tt = -b / w;
            if (tt > 0.0f && tt < 1.0f) t = tt;
        }
        thr[tid] = t;
    }
    __syncthreads();
    for (int ph = 0; ph < 128; ++ph) {   // odd-even transposition sort
        int i = 2 * tid + (ph & 1);
        if (tid < 64 && i + 1 < 128) {
            float a0 = thr[i], a1 = thr[i + 1];
            if (a0 > a1) { thr[i] = a1; thr[i + 1] = a0; }
        }
        __syncthreads();
    }
    if (tid < 128) bpts[tid] = thr[tid];
    if (tid == 0) {
        int n = 0;
        for (int i = 0; i < 128; ++i) if (thr[i] < 1.5f) n++;
        *pnIn = n;
    }
}

// ---------------------------------------------------------------------------
// K2 (multi-task by block range, 256 thr):
//  [0,256):   bf16 weight tables, n-major k-contig for MFMA B-frags.
//             wctEb[n][k]: n<128 -> W3[n][128+k] else W4[n-128][k]
//             wctRb[n][k]: n<128 -> W3[n][256+k] else W4[n-128][128+k]
//  [256,321): att piecewise tables ab3[j][h] = {A3, B3} (float2), exact
//             reassociation: att-contrib[h] = att*A3[j]+B3[j] on interval j.
//  [321,362): segment start offsets via lower_bound on sorted seg_ids.
// ---------------------------------------------------------------------------
__global__ void __launch_bounds__(256)
k2_tables(const void* __restrict__ W3w, const void* __restrict__ W4w,
          const void* __restrict__ seg_ids,
          const int* __restrict__ flag, const int* __restrict__ iflag,
          const float* __restrict__ W1w_f, const float* __restrict__ W1b_f,
          const float* __restrict__ bpts, const int* __restrict__ pnIn,
          unsigned short* __restrict__ wctEb, unsigned short* __restrict__ wctRb,
          float2* __restrict__ ab3, int* __restrict__ starts)
{
    const int bid = blockIdx.x, tid = threadIdx.x;
    const int isB = *flag;
    if (bid < 256) {
        int gid = bid * 256 + tid;
        if (gid < 32768) {
            int n = gid >> 7, k = gid & 127;
            float v = (n < 128) ? loadF(W3w, n * 384 + 128 + k, isB)
                                : loadF(W4w, (n - 128) * 256 + k, isB);
            wctEb[gid] = f2bu(v);
        } else {
            int j = gid - 32768;
            int n = j >> 7, k = j & 127;
            float v = (n < 128) ? loadF(W3w, n * 384 + 256 + k, isB)
                                : loadF(W4w, (n - 128) * 256 + 128 + k, isB);
            wctRb[j] = f2bu(v);
        }
    } else if (bid < 321) {
        __shared__ float w1s[128], b1s[128];
        const int h = tid & 127;
        if (tid < 128) { w1s[tid] = W1w_f[tid]; b1s[tid] = W1b_f[tid]; }
        __syncthreads();
        const int nIn = *pnIn;
        const int j = (bid - 256) * 2 + (tid >> 7);
        if (j <= nIn) {
            float left  = (j == 0)   ? 0.0f : bpts[j - 1];
            float right = (j == nIn) ? 1.0f : bpts[j];
            float mid = 0.5f * (left + right);
            float a = 0.0f, b = 0.0f;
            for (int k = 0; k < 128; ++k) {
                if (fmaf(mid, w1s[k], b1s[k]) > 0.0f) {
                    float w3 = loadF(W3w, h * 384 + k, isB);
                    a = fmaf(w1s[k], w3, a);
                    b = fmaf(b1s[k], w3, b);
                }
            }
            ab3[j * 128 + h] = make_float2(a, b);
        }
    } else {
        int t = (bid - 321) * 256 + tid;
        if (t <= T_SEG) {
            const int i64 = *iflag;
            int lo = 0, hi = E_EDGES;
            while (lo < hi) {
                int m = (lo + hi) >> 1;
                if (loadI(seg_ids, m, i64) < t) lo = m + 1; else hi = m;
            }
            starts[t] = lo;
        }
    }
}

// ---------------------------------------------------------------------------
// K3: fused MFMA GEMM (entity + relation projections).
// One wave = one 16x16 m-tile x one n-pair (n and n+128), K=128 in 4 steps
// of mfma_f32_16x16x32_bf16. A-frag: A[m=lane&15][k=quad*8+j] (8 consec k);
// B-frag: WT[n=lane&15][k=quad*8+j]; D: row=quad*4+r, col=lane&15.
// Output packed: out[m*128+h] = uint32{lo=bf16 P3[h], hi=bf16 P4[h]}.
// ---------------------------------------------------------------------------
__global__ void __launch_bounds__(256)
k3_gemm(const void* __restrict__ ent_raw, const void* __restrict__ rel_raw,
        const int* __restrict__ flag,
        const unsigned short* __restrict__ wctEb,
        const unsigned short* __restrict__ wctRb,
        unsigned int* __restrict__ entp2, unsigned int* __restrict__ relp2)
{
    const int isB = *flag;
    const int gw = blockIdx.x * 4 + (threadIdx.x >> 6);
    const int lane = threadIdx.x & 63;
    const int quad = lane >> 4, l16 = lane & 15;

    const void* A; const unsigned short* WT; unsigned int* out;
    int mtile, npair;
    if (gw < (N_ENT_C / 16) * 8) {           // 20000 entity wave-tasks
        A = ent_raw; WT = wctEb; out = entp2;
        mtile = gw >> 3; npair = gw & 7;
    } else {
        int g = gw - (N_ENT_C / 16) * 8;
        if (g >= (N_REL_C / 16) * 8) return; // 128 rel wave-tasks
        A = rel_raw; WT = wctRb; out = relp2;
        mtile = g >> 3; npair = g & 7;
    }

    const int mrow = mtile * 16 + l16;
    const int n3 = npair * 16 + l16;
    f32x4 acc3 = {0.f, 0.f, 0.f, 0.f}, acc4 = {0.f, 0.f, 0.f, 0.f};
    #pragma unroll
    for (int kk = 0; kk < 4; ++kk) {
        const int kb = kk * 32 + quad * 8;
        short8 av;
        if (isB) {
            av = *(const short8*)((const short*)A + mrow * 128 + kb);
        } else {
            const float* pa = (const float*)A + mrow * 128 + kb;
            float4 f0 = *(const float4*)pa;
            float4 f1 = *(const float4*)(pa + 4);
            av[0] = (short)f2bu(f0.x); av[1] = (short)f2bu(f0.y);
            av[2] = (short)f2bu(f0.z); av[3] = (short)f2bu(f0.w);
            av[4] = (short)f2bu(f1.x); av[5] = (short)f2bu(f1.y);
            av[6] = (short)f2bu(f1.z); av[7] = (short)f2bu(f1.w);
        }
        short8 bv3 = *(const short8*)((const short*)WT + n3 * 128 + kb);
        short8 bv4 = *(const short8*)((const short*)WT + (n3 + 128) * 128 + kb);
        acc3 = __builtin_amdgcn_mfma_f32_16x16x32_bf16(av, bv3, acc3, 0, 0, 0);
        acc4 = __builtin_amdgcn_mfma_f32_16x16x32_bf16(av, bv4, acc4, 0, 0, 0);
    }
    #pragma unroll
    for (int r = 0; r < 4; ++r) {
        int m = mtile * 16 + quad * 4 + r;
        int h = npair * 16 + l16;
        unsigned int w = (unsigned int)f2bu(acc3[r])
                       | ((unsigned int)f2bu(acc4[r]) << 16);
        out[m * 128 + h] = w;
    }
}

// ---------------------------------------------------------------------------
// K4: per-segment aggregation + epilogue (fp32 outputs).
// Block t = b*L+l, thread h. LDS-staged per-edge scalars (incl. att-bucket
// binary search), packed bf16-pair gathers, register accumulation.
//   outS[t] = [ ent[s_ids[b]], rel[r_ids[b]], mean(relu(P4s+P4r+b4)) ]
//   outA[t] = [ relu(sa*w1+b1), ent[s_ids[b]], mean(relu(att*A3+B3+P3s+P3r+b3)) ]
// ---------------------------------------------------------------------------
__global__ void __launch_bounds__(128)
k4_segment(const void* __restrict__ nbr_ent, const void* __restrict__ nbr_rel,
           const void* __restrict__ att_raw,
           const int* __restrict__ starts,
           const unsigned int* __restrict__ entp2,
           const unsigned int* __restrict__ relp2,
           const float2* __restrict__ ab3,
           const float* __restrict__ bpts_g, const int* __restrict__ pnIn,
           const float* __restrict__ W3b_f, const float* __restrict__ W4b_f,
           const void* __restrict__ sat_raw,
           const void* __restrict__ s_ids, const void* __restrict__ r_ids,
           const void* __restrict__ ent_raw, const void* __restrict__ rel_raw,
           const float* __restrict__ W1w_f, const float* __restrict__ W1b_f,
           const int* __restrict__ flag, const int* __restrict__ iflag,
           float* __restrict__ outS, float* __restrict__ outA)
{
    const int t = blockIdx.x, h = threadIdx.x;
    const int isB = *flag, i64 = *iflag;
    const int s = starts[t], e = starts[t + 1];

    __shared__ float bptsS[128];
    __shared__ int entS[128], relS[128], jS[128];
    __shared__ float attS[128];
    bptsS[h] = bpts_g[h];
    const int nIn = *pnIn;

    const float b3h = W3b_f[h], b4h = W4b_f[h];
    float acc3 = 0.0f, acc4 = 0.0f;

    for (int base = s; base < e; base += 128) {
        const int n = min(128, e - base);
        __syncthreads();
        if (h < n) {
            const int i = base + h;
            entS[h] = loadI(nbr_ent, i, i64);
            relS[h] = loadI(nbr_rel, i, i64);
            float att = loadF(att_raw, i, isB);
            attS[h] = att;
            int lo = 0, hi = nIn;   // bucket = count of breakpoints <= att
            while (lo < hi) {
                int m = (lo + hi) >> 1;
                if (bptsS[m] <= att) lo = m + 1; else hi = m;
            }
            jS[h] = lo;
        }
        __syncthreads();
        for (int ii = 0; ii < n; ++ii) {
            const int ent = entS[ii], rel = relS[ii], j = jS[ii];
            const float att = attS[ii];
            unsigned int ew = entp2[ent * 128 + h];   // HBM/L3 gather (4 B)
            unsigned int rw = relp2[rel * 128 + h];   // L2-hot (128 KB table)
            float2 ab = ab3[j * 128 + h];             // L2-hot (132 KB table)
            float p3s = bu2f((unsigned short)(ew & 0xFFFFu));
            float p4s = bu2f((unsigned short)(ew >> 16));
            float p3r = bu2f((unsigned short)(rw & 0xFFFFu));
            float p4r = bu2f((unsigned short)(rw >> 16));
            float z3 = fmaf(att, ab.x, ab.y) + p3s + p3r + b3h;
            float z4 = p4s + p4r + b4h;
            acc3 += fmaxf(z3, 0.0f);
            acc4 += fmaxf(z4, 0.0f);
        }
    }

    const int cnt = e - s;
    const float inv = (cnt > 0) ? (1.0f / (float)cnt) : 1.0f;
    const int b = t / L_SEQ;
    const int sid = loadI(s_ids, b, i64);
    const int rid = loadI(r_ids, b, i64);
    const float se = loadF(ent_raw, sid * 128 + h, isB);
    const float sr = loadF(rel_raw, rid * 128 + h, isB);
    const float sa = loadF(sat_raw, t, isB);
    const float sae = fmaxf(fmaf(sa, W1w_f[h], W1b_f[h]), 0.0f);

    const size_t bs = (size_t)t * 384;
    outS[bs + h]       = se;
    outS[bs + 128 + h] = sr;
    outS[bs + 256 + h] = acc4 * inv;
    outA[bs + h]       = sae;
    outA[bs + 128 + h] = se;
    outA[bs + 256 + h] = acc3 * inv;
}

// ---------------------------------------------------------------------------
extern "C" void kernel_launch(void* const* d_in, const int* in_sizes, int n_in,
                              void* d_out, int out_size, void* d_ws, size_t ws_size,
                              hipStream_t stream)
{
    const void* nbr_ent = d_in[0];
    const void* nbr_rel = d_in[1];
    const void* nbr_att = d_in[2];
    const void* seg_ids = d_in[3];
    const void* self_att = d_in[4];
    const void* s_ids = d_in[5];
    const void* r_ids = d_in[6];
    const void* ent_embeds = d_in[7];
    const void* rel_embeds = d_in[8];
    const void* W1w = d_in[9];
    const void* W1b = d_in[10];
    const void* W3w = d_in[11];
    const void* W3b = d_in[12];
    const void* W4w = d_in[13];
    const void* W4b = d_in[14];

    // workspace carve-up (~21 MB total; round-5 tier-0 proved ws >= ~43 MB)
    char* ws = (char*)d_ws;
    size_t off = 0;
    auto alloc = [&](size_t bytes) -> void* {
        void* p = ws + off;
        off = (off + bytes + 255) & ~(size_t)255;
        return p;
    };
    int*   flag   = (int*)alloc(4);
    int*   iflag  = (int*)alloc(4);
    int*   pnIn   = (int*)alloc(4);
    float* W1w_f  = (float*)alloc(128 * 4);
    float* W1b_f  = (float*)alloc(128 * 4);
    float* W3b_f  = (float*)alloc(128 * 4);
    float* W4b_f  = (float*)alloc(128 * 4);
    float* bpts   = (float*)alloc(128 * 4);
    int*   starts = (int*)alloc((T_SEG + 1) * 4);
    unsigned short* wctEb = (unsigned short*)alloc(256 * 128 * 2);
    unsigned short* wctRb = (unsigned short*)alloc(256 * 128 * 2);
    float2* ab3   = (float2*)alloc(129 * 128 * 8);
    unsigned int* entp2 = (unsigned int*)alloc((size_t)N_ENT_C * 128 * 4); // 20.48 MB
    unsigned int* relp2 = (unsigned int*)alloc((size_t)N_REL_C * 128 * 4);

    float* outS = (float*)d_out;
    float* outA = outS + (size_t)T_SEG * 384;

    // K1: dtype detection + scalars + sorted breakpoints
    k1_prep<<<1, 256, 0, stream>>>(nbr_att, s_ids, W1w, W1b, W3b, W4b,
                                   flag, iflag, W1w_f, W1b_f, W3b_f, W4b_f,
                                   bpts, pnIn);

    // K2: weight tables + att tables + segment starts (fused multi-task)
    k2_tables<<<362, 256, 0, stream>>>(W3w, W4w, seg_ids, flag, iflag,
                                       W1w_f, W1b_f, bpts, pnIn,
                                       wctEb, wctRb, ab3, starts);

    // K3: fused entity+relation MFMA projection GEMM
    {
        int waves = (N_ENT_C / 16) * 8 + (N_REL_C / 16) * 8;  // 20128
        k3_gemm<<<(waves + 3) / 4, 256, 0, stream>>>(
            ent_embeds, rel_embeds, flag, wctEb, wctRb, entp2, relp2);
    }

    // K4: per-segment aggregation + epilogue
    k4_segment<<<T_SEG, 128, 0, stream>>>(
        nbr_ent, nbr_rel, nbr_att, starts, entp2, relp2, ab3, bpts, pnIn,
        W3b_f, W4b_f, self_att, s_ids, r_ids, ent_embeds, rel_embeds,
        W1w_f, W1b_f, flag, iflag, outS, outA);
}

// Round 7
// 189.776 us; speedup vs baseline: 1.6250x; 1.1381x over previous
//
#include <hip/hip_runtime.h>
#include <hip/hip_bf16.h>

// Problem constants (from reference)
#define E_EDGES 262144
#define B_SAMP  1024
#define L_SEQ   10
#define T_SEG   (B_SAMP * L_SEQ)   // 10240 segments
#define H_DIM   128
#define N_ENT_C 40000
#define N_REL_C 256

typedef __attribute__((ext_vector_type(8))) short short8;   // 8 bf16 (4 VGPRs)
typedef __attribute__((ext_vector_type(4))) float f32x4;

__device__ __forceinline__ float b2f(__hip_bfloat16 x) { return __bfloat162float(x); }
__device__ __forceinline__ unsigned short f2bu(float x) {
    return __bfloat16_as_ushort(__float2bfloat16(x));
}
__device__ __forceinline__ float bu2f(unsigned short u) {
    return b2f(__ushort_as_bfloat16(u));
}

// Float load with runtime-detected storage (bf16 vs float32).
__device__ __forceinline__ float loadF(const void* base, int idx, int isB16) {
    if (isB16) return b2f(((const __hip_bfloat16*)base)[idx]);
    return ((const float*)base)[idx];
}
// Integer load with runtime-detected width (int64 vs int32).
__device__ __forceinline__ int loadI(const void* base, int idx, int is64) {
    if (is64) return (int)(((const long long*)base)[idx]);
    return ((const int*)base)[idx];
}

// Per-block dtype detection (cheap, deterministic; removes cross-block deps).
// bf16 uniform[0,1): ~100% of first 2048 words <= 0x3F80; f32: ~62%.
// int64: odd int32 words of s_ids are zero high-words.
__device__ __forceinline__ void detect_dtypes(const void* att_raw,
                                              const void* sid_raw,
                                              int tid, int& isB, int& i64)
{
    __shared__ int cF, cI;
    if (tid == 0) { cF = 0; cI = 0; }
    __syncthreads();
    const unsigned short* pa = (const unsigned short*)att_raw;
    int c = 0;
    for (int i = tid; i < 2048; i += 256) if (pa[i] <= 0x3F80u) c++;
    if (c) atomicAdd(&cF, c);
    const int* ps = (const int*)sid_raw;
    c = 0;
    for (int i = tid; i < 512; i += 256) if (ps[2 * i + 1] == 0) c++;
    if (c) atomicAdd(&cI, c);
    __syncthreads();
    isB = (cF >= 1900) ? 1 : 0;
    i64 = (cI >= 256) ? 1 : 0;
}

// ---------------------------------------------------------------------------
// K_A: all prep in one launch, blocks fully independent (each self-detects
// dtypes; breakpoint-dependent blocks recompute breakpoints locally via a
// barrier-free O(128^2) rank sort).
//  bid [0,256):   bf16 weight tables, n-major k-contig for MFMA B-frags.
//                 wctEb[n][k]: n<128 -> W3[n][128+k] else W4[n-128][k]
//                 wctRb[n][k]: n<128 -> W3[n][256+k] else W4[n-128][128+k]
//  bid [256,321): att piecewise tables ab3[j][h] = {A3,B3} (float2); exact
//                 reassociation: att-contrib[h] = att*A3[j]+B3[j], interval j.
//  bid [321,362): segment start offsets via lower_bound on sorted seg_ids.
//  bid 362:       global scalar vectors + sorted bpts + pnIn + dtype flags
//                 (consumed by K_B / K_C).
// ---------------------------------------------------------------------------
__global__ void __launch_bounds__(256)
ka_prep(const void* __restrict__ W3w, const void* __restrict__ W4w,
        const void* __restrict__ W1w, const void* __restrict__ W1b,
        const void* __restrict__ W3b, const void* __restrict__ W4b,
        const void* __restrict__ seg_ids,
        const void* __restrict__ att_raw, const void* __restrict__ sid_raw,
        unsigned short* __restrict__ wctEb, unsigned short* __restrict__ wctRb,
        float2* __restrict__ ab3, int* __restrict__ starts,
        float* __restrict__ W1w_f, float* __restrict__ W1b_f,
        float* __restrict__ W3b_f, float* __restrict__ W4b_f,
        float* __restrict__ bpts, int* __restrict__ pnIn,
        int* __restrict__ flag, int* __restrict__ iflag)
{
    const int bid = blockIdx.x, tid = threadIdx.x;
    int isB, i64;
    detect_dtypes(att_raw, sid_raw, tid, isB, i64);

    if (bid < 256) {
        int gid = bid * 256 + tid;
        if (gid < 32768) {
            int n = gid >> 7, k = gid & 127;
            float v = (n < 128) ? loadF(W3w, n * 384 + 128 + k, isB)
                                : loadF(W4w, (n - 128) * 256 + k, isB);
            wctEb[gid] = f2bu(v);
        } else {
            int j = gid - 32768;
            int n = j >> 7, k = j & 127;
            float v = (n < 128) ? loadF(W3w, n * 384 + 256 + k, isB)
                                : loadF(W4w, (n - 128) * 256 + 128 + k, isB);
            wctRb[j] = f2bu(v);
        }
        return;
    }

    if (bid < 321 || bid == 362) {
        // local breakpoints: thr_k = -b1k/w1k if in (0,1) else sentinel 2.0
        __shared__ float w1s[128], b1s[128], srt[128];
        __shared__ int nInS;
        if (tid < 128) {
            float w = loadF(W1w, tid, isB);
            float b = loadF(W1b, tid, isB);
            w1s[tid] = w; b1s[tid] = b;
        }
        __syncthreads();
        if (tid < 128) {
            float w = w1s[tid], b = b1s[tid];
            float t = 2.0f;
            if (w != 0.0f) {
                float tt = -b / w;
                if (tt > 0.0f && tt < 1.0f) t = tt;
            }
            srt[tid] = t;   // temporarily unsorted
        }
        __syncthreads();
        float myt = 0.0f; int rank = 0, n = 0;
        if (tid < 128) {
            myt = srt[tid];
            for (int j = 0; j < 128; ++j) {
                float v = srt[j];
                rank += (v < myt) || (v == myt && j < tid);
                n += (v < 1.5f);
            }
        }
        __syncthreads();
        if (tid < 128) srt[rank] = myt;     // now sorted
        if (tid == 0) nInS = n;
        __syncthreads();
        const int nIn = nInS;

        if (bid == 362) {
            if (tid < 128) {
                W1w_f[tid] = w1s[tid];
                W1b_f[tid] = b1s[tid];
                W3b_f[tid] = loadF(W3b, tid, isB);
                W4b_f[tid] = loadF(W4b, tid, isB);
                bpts[tid] = srt[tid];
            }
            if (tid == 0) { *pnIn = nIn; *flag = isB; *iflag = i64; }
            return;
        }
        // ab3 blocks: j = (bid-256)*2 + (tid>>7), h = tid&127
        const int j = (bid - 256) * 2 + (tid >> 7);
        const int h = tid & 127;
        if (j <= nIn) {
            float left  = (j == 0)   ? 0.0f : srt[j - 1];
            float right = (j == nIn) ? 1.0f : srt[j];
            float mid = 0.5f * (left + right);
            float a = 0.0f, b = 0.0f;
            for (int k = 0; k < 128; ++k) {
                if (fmaf(mid, w1s[k], b1s[k]) > 0.0f) {
                    float w3 = loadF(W3w, h * 384 + k, isB);
                    a = fmaf(w1s[k], w3, a);
                    b = fmaf(b1s[k], w3, b);
                }
            }
            ab3[j * 128 + h] = make_float2(a, b);
        }
        return;
    }

    // starts blocks
    int t = (bid - 321) * 256 + tid;
    if (t <= T_SEG) {
        int lo = 0, hi = E_EDGES;
        while (lo < hi) {
            int m = (lo + hi) >> 1;
            if (loadI(seg_ids, m, i64) < t) lo = m + 1; else hi = m;
        }
        starts[t] = lo;
    }
}

// ---------------------------------------------------------------------------
// K_B: fused MFMA projection GEMM, LDS-staged.
// Block = 64 rows (4 waves x 16 rows), coalesced A staging f32/bf16 -> bf16
// LDS tile (row pad +8 bf16 to break bank aliasing). Each wave: 16 rows x
// all 8 n-pairs (n, n+128), K=128 in 4 MFMA steps -> 64 MFMAs/wave.
// A-frag: A[m=lane&15][k=quad*8+j]; B-frag: WT[n=lane&15][k=quad*8+j];
// D: row=quad*4+r, col=lane&15.
// Output packed: out[m*128+h] = uint32{lo=bf16 P3[h], hi=bf16 P4[h]}.
// ---------------------------------------------------------------------------
#define KB_ENT_BLOCKS (N_ENT_C / 64)   // 625
#define KB_REL_BLOCKS (N_REL_C / 64)   // 4

__global__ void __launch_bounds__(256)
kb_gemm(const void* __restrict__ ent_raw, const void* __restrict__ rel_raw,
        const int* __restrict__ flag,
        const unsigned short* __restrict__ wctEb,
        const unsigned short* __restrict__ wctRb,
        unsigned int* __restrict__ entp2, unsigned int* __restrict__ relp2)
{
    const int isB = *flag;
    const int bid = blockIdx.x, tid = threadIdx.x;

    const void* A; const unsigned short* WT; unsigned int* out; int m0;
    if (bid < KB_ENT_BLOCKS) { A = ent_raw; WT = wctEb; out = entp2; m0 = bid * 64; }
    else { A = rel_raw; WT = wctRb; out = relp2; m0 = (bid - KB_ENT_BLOCKS) * 64; }

    __shared__ unsigned short As[64][136];   // +8 pad: 272 B row, 16B-aligned

    if (isB) {
        // 8192 bf16 = 1024 short8 vectors, coalesced
        for (int v = tid; v < 1024; v += 256) {
            int e = v * 8, r = e >> 7, cc = e & 127;
            short8 x = *(const short8*)((const short*)A + m0 * 128 + e);
            *(short8*)&As[r][cc] = x;
        }
    } else {
        // 8192 f32 = 2048 float4 vectors, coalesced; convert to bf16
        for (int v = tid; v < 2048; v += 256) {
            int e = v * 4, r = e >> 7, cc = e & 127;
            float4 f = *(const float4*)((const float*)A + m0 * 128 + e);
            unsigned int lo = (unsigned int)f2bu(f.x) | ((unsigned int)f2bu(f.y) << 16);
            unsigned int hi = (unsigned int)f2bu(f.z) | ((unsigned int)f2bu(f.w) << 16);
            *(uint2*)&As[r][cc] = make_uint2(lo, hi);
        }
    }
    __syncthreads();

    const int wave = tid >> 6, lane = tid & 63;
    const int quad = lane >> 4, l16 = lane & 15;

    f32x4 acc3[8], acc4[8];
    #pragma unroll
    for (int np = 0; np < 8; ++np) {
        acc3[np] = (f32x4){0.f, 0.f, 0.f, 0.f};
        acc4[np] = (f32x4){0.f, 0.f, 0.f, 0.f};
    }

    #pragma unroll
    for (int kk = 0; kk < 4; ++kk) {
        const int kb = kk * 32 + quad * 8;
        short8 av = *(const short8*)&As[wave * 16 + l16][kb];
        #pragma unroll
        for (int np = 0; np < 8; ++np) {
            const short* bp = (const short*)WT + (np * 16 + l16) * 128 + kb;
            short8 bv3 = *(const short8*)bp;
            short8 bv4 = *(const short8*)(bp + 128 * 128);
            acc3[np] = __builtin_amdgcn_mfma_f32_16x16x32_bf16(av, bv3, acc3[np], 0, 0, 0);
            acc4[np] = __builtin_amdgcn_mfma_f32_16x16x32_bf16(av, bv4, acc4[np], 0, 0, 0);
        }
    }

    #pragma unroll
    for (int np = 0; np < 8; ++np) {
        #pragma unroll
        for (int r = 0; r < 4; ++r) {
            int m = m0 + wave * 16 + quad * 4 + r;
            int h = np * 16 + l16;
            unsigned int w = (unsigned int)f2bu(acc3[np][r])
                           | ((unsigned int)f2bu(acc4[np][r]) << 16);
            out[m * 128 + h] = w;
        }
    }
}

// ---------------------------------------------------------------------------
// K_C: per-segment aggregation + epilogue (fp32 outputs).
// Block t = b*L+l, thread h. LDS-staged per-edge scalars (incl. att-bucket
// binary search), packed bf16-pair gathers, register accumulation.
//   outS[t] = [ ent[s_ids[b]], rel[r_ids[b]], mean(relu(P4s+P4r+b4)) ]
//   outA[t] = [ relu(sa*w1+b1), ent[s_ids[b]], mean(relu(att*A3+B3+P3s+P3r+b3)) ]
// ---------------------------------------------------------------------------
__global__ void __launch_bounds__(128)
kc_segment(const void* __restrict__ nbr_ent, const void* __restrict__ nbr_rel,
           const void* __restrict__ att_raw,
           const int* __restrict__ starts,
           const unsigned int* __restrict__ entp2,
           const unsigned int* __restrict__ relp2,
           const float2* __restrict__ ab3,
           const float* __restrict__ bpts_g, const int* __restrict__ pnIn,
           const float* __restrict__ W3b_f, const float* __restrict__ W4b_f,
           const void* __restrict__ sat_raw,
           const void* __restrict__ s_ids, const void* __restrict__ r_ids,
           const void* __restrict__ ent_raw, const void* __restrict__ rel_raw,
           const float* __restrict__ W1w_f, const float* __restrict__ W1b_f,
           const int* __restrict__ flag, const int* __restrict__ iflag,
           float* __restrict__ outS, float* __restrict__ outA)
{
    const int t = blockIdx.x, h = threadIdx.x;
    const int isB = *flag, i64 = *iflag;
    const int s = starts[t], e = starts[t + 1];

    __shared__ float bptsS[128];
    __shared__ int entS[128], relS[128], jS[128];
    __shared__ float attS[128];
    bptsS[h] = bpts_g[h];
    const int nIn = *pnIn;

    const float b3h = W3b_f[h], b4h = W4b_f[h];
    float acc3 = 0.0f, acc4 = 0.0f;

    for (int base = s; base < e; base += 128) {
        const int n = min(128, e - base);
        __syncthreads();
        if (h < n) {
            const int i = base + h;
            entS[h] = loadI(nbr_ent, i, i64);
            relS[h] = loadI(nbr_rel, i, i64);
            float att = loadF(att_raw, i, isB);
            attS[h] = att;
            int lo = 0, hi = nIn;   // bucket = count of breakpoints <= att
            while (lo < hi) {
                int m = (lo + hi) >> 1;
                if (bptsS[m] <= att) lo = m + 1; else hi = m;
            }
            jS[h] = lo;
        }
        __syncthreads();
        for (int ii = 0; ii < n; ++ii) {
            const int ent = entS[ii], rel = relS[ii], j = jS[ii];
            const float att = attS[ii];
            unsigned int ew = entp2[ent * 128 + h];   // L3/HBM gather (4 B/lane)
            unsigned int rw = relp2[rel * 128 + h];   // L2-hot (128 KB table)
            float2 ab = ab3[j * 128 + h];             // L2-hot (132 KB table)
            float p3s = bu2f((unsigned short)(ew & 0xFFFFu));
            float p4s = bu2f((unsigned short)(ew >> 16));
            float p3r = bu2f((unsigned short)(rw & 0xFFFFu));
            float p4r = bu2f((unsigned short)(rw >> 16));
            float z3 = fmaf(att, ab.x, ab.y) + p3s + p3r + b3h;
            float z4 = p4s + p4r + b4h;
            acc3 += fmaxf(z3, 0.0f);
            acc4 += fmaxf(z4, 0.0f);
        }
    }

    const int cnt = e - s;
    const float inv = (cnt > 0) ? (1.0f / (float)cnt) : 1.0f;
    const int b = t / L_SEQ;
    const int sid = loadI(s_ids, b, i64);
    const int rid = loadI(r_ids, b, i64);
    const float se = loadF(ent_raw, sid * 128 + h, isB);
    const float sr = loadF(rel_raw, rid * 128 + h, isB);
    const float sa = loadF(sat_raw, t, isB);
    const float sae = fmaxf(fmaf(sa, W1w_f[h], W1b_f[h]), 0.0f);

    const size_t bs = (size_t)t * 384;
    outS[bs + h]       = se;
    outS[bs + 128 + h] = sr;
    outS[bs + 256 + h] = acc4 * inv;
    outA[bs + h]       = sae;
    outA[bs + 128 + h] = se;
    outA[bs + 256 + h] = acc3 * inv;
}

// ---------------------------------------------------------------------------
extern "C" void kernel_launch(void* const* d_in, const int* in_sizes, int n_in,
                              void* d_out, int out_size, void* d_ws, size_t ws_size,
                              hipStream_t stream)
{
    const void* nbr_ent = d_in[0];
    const void* nbr_rel = d_in[1];
    const void* nbr_att = d_in[2];
    const void* seg_ids = d_in[3];
    const void* self_att = d_in[4];
    const void* s_ids = d_in[5];
    const void* r_ids = d_in[6];
    const void* ent_embeds = d_in[7];
    const void* rel_embeds = d_in[8];
    const void* W1w = d_in[9];
    const void* W1b = d_in[10];
    const void* W3w = d_in[11];
    const void* W3b = d_in[12];
    const void* W4w = d_in[13];
    const void* W4b = d_in[14];

    // workspace carve-up (~21 MB; round-5 tier-0 proved ws >= ~43 MB)
    char* ws = (char*)d_ws;
    size_t off = 0;
    auto alloc = [&](size_t bytes) -> void* {
        void* p = ws + off;
        off = (off + bytes + 255) & ~(size_t)255;
        return p;
    };
    int*   flag   = (int*)alloc(4);
    int*   iflag  = (int*)alloc(4);
    int*   pnIn   = (int*)alloc(4);
    float* W1w_f  = (float*)alloc(128 * 4);
    float* W1b_f  = (float*)alloc(128 * 4);
    float* W3b_f  = (float*)alloc(128 * 4);
    float* W4b_f  = (float*)alloc(128 * 4);
    float* bpts   = (float*)alloc(128 * 4);
    int*   starts = (int*)alloc((T_SEG + 1) * 4);
    unsigned short* wctEb = (unsigned short*)alloc(256 * 128 * 2);
    unsigned short* wctRb = (unsigned short*)alloc(256 * 128 * 2);
    float2* ab3   = (float2*)alloc(129 * 128 * 8);
    unsigned int* entp2 = (unsigned int*)alloc((size_t)N_ENT_C * 128 * 4); // 20.48 MB
    unsigned int* relp2 = (unsigned int*)alloc((size_t)N_REL_C * 128 * 4);

    float* outS = (float*)d_out;
    float* outA = outS + (size_t)T_SEG * 384;

    // K_A: all prep (dtype-detect per block; wct tables + ab3 + starts + scalars)
    ka_prep<<<363, 256, 0, stream>>>(W3w, W4w, W1w, W1b, W3b, W4b,
                                     seg_ids, nbr_att, s_ids,
                                     wctEb, wctRb, ab3, starts,
                                     W1w_f, W1b_f, W3b_f, W4b_f,
                                     bpts, pnIn, flag, iflag);

    // K_B: fused entity+relation MFMA projection GEMM (LDS-staged)
    kb_gemm<<<KB_ENT_BLOCKS + KB_REL_BLOCKS, 256, 0, stream>>>(
        ent_embeds, rel_embeds, flag, wctEb, wctRb, entp2, relp2);

    // K_C: per-segment aggregation + epilogue
    kc_segment<<<T_SEG, 128, 0, stream>>>(
        nbr_ent, nbr_rel, nbr_att, starts, entp2, relp2, ab3, bpts, pnIn,
        W3b_f, W4b_f, self_att, s_ids, r_ids, ent_embeds, rel_embeds,
        W1w_f, W1b_f, flag, iflag, outS, outA);
}